// Round 4
// baseline (724.812 us; speedup 1.0000x reference)
//
#include <hip/hip_runtime.h>
#include <hip/hip_bf16.h>

typedef float  f32x4  __attribute__((ext_vector_type(4)));
typedef __bf16 bf16x8 __attribute__((ext_vector_type(8)));

#define SCALE_QK 0.17677669529663687f  /* 32^-0.5 (reference uses DIM_HEAD, not per-head dim) */

// B=131072, L=4, dim=256, inner=32, heads=4, dh=8
// rows = 524288 ; 16-row tiles = 32768 ; grid 1024 x 4 waves x 8 tiles
// JOURNAL: __launch_bounds__ 2nd arg = min BLOCKS/CU (CUDA semantics) on this
// toolchain: r2 (512,4)->cap 64 VGPR + huge spill; r3 (512,2)->cap 128 with
// marginal spill traffic. (256,3) -> 12 waves/CU -> cap ~170.

template<int CTRL>
__device__ __forceinline__ float dpp_add(float x) {
  int xi = __builtin_bit_cast(int, x);
  int yi = __builtin_amdgcn_mov_dpp(xi, CTRL, 0xF, 0xF, true);
  return x + __builtin_bit_cast(float, yi);
}

// ---------- prekernel: pack frag-ordered bf16 weights into d_ws ----------
// item = f*64 + lane, f in [0,64): wsf[item*8 + j]
// f in [0,48): GEMM1 frag (kt=f/6, ct=f%6): col n=ct*16+c, k=kt*32+g*8+j
// f in [48,64): Wo frag ct=f-48: col n=ct*16+c, k=g*8+j
__global__ void pack_weights(const float* __restrict__ Wq, const float* __restrict__ Wkv,
                             const float* __restrict__ Wo, __bf16* __restrict__ wsf) {
  const int item = blockIdx.x * 256 + threadIdx.x;   // 4096 items
  const int f = item >> 6, lane = item & 63;
  const int g = lane >> 4, c = lane & 15;
  union { bf16x8 v; __bf16 h[8]; } vv;
  if (f < 48) {
    const int kt = f / 6, ct = f - kt * 6;
    const int n = ct * 16 + c;
    #pragma unroll
    for (int j = 0; j < 8; ++j) {
      const int k = kt * 32 + g * 8 + j;
      vv.h[j] = (__bf16)((n < 32) ? Wq[k * 32 + n] : Wkv[k * 64 + (n - 32)]);
    }
  } else {
    const int ct = f - 48;
    const int n = ct * 16 + c;
    #pragma unroll
    for (int j = 0; j < 8; ++j) vv.h[j] = (__bf16)Wo[(g * 8 + j) * 256 + n];
  }
  *(bf16x8*)&wsf[item * 8] = vv.v;
}

// ---------- main fused kernel ----------
#define FRO(ct) (*(const bf16x8*)&wo_frag[((ct) * 64 + lane) * 8])

__global__ __launch_bounds__(256, 3) void fused_stattn(
    const float* __restrict__ x, const __bf16* __restrict__ wsf,
    const float* __restrict__ bo, const float* __restrict__ pe,
    float* __restrict__ out) {
  __shared__ __align__(16) __bf16 wo_frag[16 * 64 * 8];  // 16 KiB (frags 48..63)
  __shared__ __align__(16) __bf16 ao_lds[4][16][40];     // per-wave bounce
  __shared__ __align__(16) float bo_lds[256];
  __shared__ float pe_lds[64];

  const int tid  = threadIdx.x;
  const int lane = tid & 63;
  const int wv   = tid >> 6;
  const int g    = lane >> 4;
  const int c    = lane & 15;

  // prologue: Wo frags ws -> LDS (16 KiB), bo, pe
  #pragma unroll
  for (int it = 0; it < 4; ++it) {
    const int idx = it * 256 + tid;  // 1024 chunks of 16 B
    *(bf16x8*)&wo_frag[idx * 8] = *(const bf16x8*)&wsf[(48 * 64 + idx) * 8];
  }
  bo_lds[tid] = bo[tid];
  if (tid < 64) pe_lds[tid] = pe[tid];
  __syncthreads();

  const bf16x8* wq = (const bf16x8*)wsf;      // GEMM1 frag f at wq[f*64 + lane]

  const int slot  = blockIdx.x * 4 + wv;      // 0..4095
  const int tile0 = slot * 8;
  const f32x4* xv = (const f32x4*)x;          // row stride = 64 float4s (1 KiB)

  f32x4 xbuf[16];
  {
    const int base = (tile0 * 16 + c) * 64 + g * 2;
    #pragma unroll
    for (int kt = 0; kt < 8; ++kt) {
      xbuf[2*kt]   = xv[base + kt*8];
      xbuf[2*kt+1] = xv[base + kt*8 + 1];
    }
  }

  for (int t = 0; t < 8; ++t) {
    const int tile = tile0 + t;

    // ---- GEMM1: x[16x256] @ Wqkv[256x96]; B-frags streamed from L2 ----
    f32x4 acc0 = {0,0,0,0}, acc1 = {0,0,0,0}, acc2 = {0,0,0,0};
    f32x4 acc3 = {0,0,0,0}, acc4 = {0,0,0,0}, acc5 = {0,0,0,0};
    #pragma unroll
    for (int kt = 0; kt < 8; ++kt) {
      const bf16x8 w0 = wq[(kt*6+0)*64 + lane];
      const bf16x8 w1 = wq[(kt*6+1)*64 + lane];
      const bf16x8 w2 = wq[(kt*6+2)*64 + lane];
      const bf16x8 w3 = wq[(kt*6+3)*64 + lane];
      const bf16x8 w4 = wq[(kt*6+4)*64 + lane];
      const bf16x8 w5 = wq[(kt*6+5)*64 + lane];
      union { bf16x8 v; __bf16 h[8]; } af;    // A-frag: row=c, k = kt*32 + g*8 + j
      #pragma unroll
      for (int j = 0; j < 4; ++j) {
        af.h[j]   = (__bf16)xbuf[2*kt][j];
        af.h[4+j] = (__bf16)xbuf[2*kt+1][j];
      }
      acc0 = __builtin_amdgcn_mfma_f32_16x16x32_bf16(af.v, w0, acc0, 0,0,0);
      acc1 = __builtin_amdgcn_mfma_f32_16x16x32_bf16(af.v, w1, acc1, 0,0,0);
      acc2 = __builtin_amdgcn_mfma_f32_16x16x32_bf16(af.v, w2, acc2, 0,0,0);
      acc3 = __builtin_amdgcn_mfma_f32_16x16x32_bf16(af.v, w3, acc3, 0,0,0);
      acc4 = __builtin_amdgcn_mfma_f32_16x16x32_bf16(af.v, w4, acc4, 0,0,0);
      acc5 = __builtin_amdgcn_mfma_f32_16x16x32_bf16(af.v, w5, acc5, 0,0,0);
    }

    // ---- x prefetch for t+1: issue ALL 16 HBM loads now, so GEMM1's per-kt
    //      w-frag vmcnt waits (in-order!) never drain pending HBM loads ----
    {
      const int ntile = (tile + 1 < 32768) ? tile + 1 : tile;
      const int nbase = (ntile * 16 + c) * 64 + g * 2;
      #pragma unroll
      for (int kt = 0; kt < 8; ++kt) {
        xbuf[2*kt]   = xv[nbase + kt*8];
        xbuf[2*kt+1] = xv[nbase + kt*8 + 1];
      }
    }

    // ---- attention (in registers; 8-lane head-dim reduce via DPP) ----
    const int h0 = c >> 3;
    float ao0[4], ao1[4];
    #pragma unroll
    for (int p = 0; p < 2; ++p) {
      const f32x4 qa = p ? acc1 : acc0;
      const f32x4 ka = p ? acc3 : acc2;
      const f32x4 va = p ? acc5 : acc4;
      const int ph = 2 * p + h0;
      float sim[4][4];
      #pragma unroll
      for (int i = 0; i < 4; ++i)
        #pragma unroll
        for (int j = 0; j < 4; ++j) {
          float pr = qa[i] * ka[j];
          pr = dpp_add<0xB1>(pr);             // quad_perm xor1
          pr = dpp_add<0x4E>(pr);             // quad_perm xor2
          pr = dpp_add<0x141>(pr);            // row_half_mirror
          sim[i][j] = pr * SCALE_QK + pe_lds[ph * 16 + i * 4 + j];
        }
      #pragma unroll
      for (int i = 0; i < 4; ++i) {
        const float m = fmaxf(fmaxf(sim[i][0], sim[i][1]), fmaxf(sim[i][2], sim[i][3]));
        const float e0 = __expf(sim[i][0] - m), e1 = __expf(sim[i][1] - m);
        const float e2 = __expf(sim[i][2] - m), e3 = __expf(sim[i][3] - m);
        const float rs = 1.0f / (e0 + e1 + e2 + e3);
        const float o  = (e0*va[0] + e1*va[1] + e2*va[2] + e3*va[3]) * rs;
        if (p) ao1[i] = o; else ao0[i] = o;
      }
    }

    // ---- bounce C-layout -> B-frag layout for GEMM2 (per-wave private) ----
    #pragma unroll
    for (int i = 0; i < 4; ++i) {
      ao_lds[wv][g*4 + i][c]      = (__bf16)ao0[i];
      ao_lds[wv][g*4 + i][16 + c] = (__bf16)ao1[i];
    }
    const bf16x8 a2 = *(const bf16x8*)&ao_lds[wv][c][g * 8];  // col=c(=x-row), k=g*8+j

    // ---- GEMM2 (swapped): Wo^T @ ao^T, bias as C-input, float4 stores ----
    const int orow = (tile * 16 + c) * 256;
    #pragma unroll
    for (int ct = 0; ct < 16; ++ct) {
      const f32x4 bv = *(const f32x4*)&bo_lds[ct * 16 + g * 4];
      f32x4 o = __builtin_amdgcn_mfma_f32_16x16x32_bf16(FRO(ct), a2, bv, 0,0,0);
      *(f32x4*)&out[orow + ct * 16 + g * 4] = o;
    }
  }
}

extern "C" void kernel_launch(void* const* d_in, const int* in_sizes, int n_in,
                              void* d_out, int out_size, void* d_ws, size_t ws_size,
                              hipStream_t stream) {
  const float* x   = (const float*)d_in[0];
  const float* Wq  = (const float*)d_in[1];
  const float* Wkv = (const float*)d_in[2];
  const float* Wo  = (const float*)d_in[3];
  const float* bo  = (const float*)d_in[4];
  const float* pe  = (const float*)d_in[5];
  float* out = (float*)d_out;
  __bf16* wsf = (__bf16*)d_ws;   // 64 KiB of frag-ordered bf16 weights

  hipLaunchKernelGGL(pack_weights, dim3(16), dim3(256), 0, stream, Wq, Wkv, Wo, wsf);
  hipLaunchKernelGGL(fused_stattn, dim3(1024), dim3(256), 0, stream,
                     x, wsf, bo, pe, out);
}

// Round 5
// 478.320 us; speedup vs baseline: 1.5153x; 1.5153x over previous
//
#include <hip/hip_runtime.h>
#include <hip/hip_bf16.h>

typedef float  f32x4  __attribute__((ext_vector_type(4)));
typedef __bf16 bf16x8 __attribute__((ext_vector_type(8)));

#define SCALE_QK 0.17677669529663687f  /* 32^-0.5 (reference uses DIM_HEAD, not per-head dim) */

// B=131072, L=4, dim=256, inner=32, heads=4, dh=8
// rows = 524288 ; 16-row tiles = 32768 ; grid 512 x 8 waves x 8 tiles
// JOURNAL (launch-bounds trap): 2nd arg configs implying >16 waves/CU force a
// small VGPR cap -> scratch spill (r2 (512,4)->64 VGPR, 2.5GB traffic;
// r4 (256,3)->84 VGPR, 2.25GB). Natural footprint ~128 (r1, clean). This
// round: shrink natural VGPR (~110) by converting x to bf16 at the load
// boundary instead of keeping 64 fp32 regs live; then (512,2)'s 128 cap fits.

template<int CTRL>
__device__ __forceinline__ float dpp_add(float x) {
  int xi = __builtin_bit_cast(int, x);
  int yi = __builtin_amdgcn_mov_dpp(xi, CTRL, 0xF, 0xF, true);
  return x + __builtin_bit_cast(float, yi);
}

// ---------- prekernel: pack frag-ordered bf16 weights into d_ws ----------
// item = f*64 + lane, f in [0,64): wsf[item*8 + j]
// f in [0,48): GEMM1 frag (kt=f/6, ct=f%6): col n=ct*16+c, k=kt*32+g*8+j
// f in [48,64): Wo frag ct=f-48: col n=ct*16+c, k=g*8+j
__global__ void pack_weights(const float* __restrict__ Wq, const float* __restrict__ Wkv,
                             const float* __restrict__ Wo, __bf16* __restrict__ wsf) {
  const int item = blockIdx.x * 256 + threadIdx.x;   // 4096 items
  const int f = item >> 6, lane = item & 63;
  const int g = lane >> 4, c = lane & 15;
  union { bf16x8 v; __bf16 h[8]; } vv;
  if (f < 48) {
    const int kt = f / 6, ct = f - kt * 6;
    const int n = ct * 16 + c;
    #pragma unroll
    for (int j = 0; j < 8; ++j) {
      const int k = kt * 32 + g * 8 + j;
      vv.h[j] = (__bf16)((n < 32) ? Wq[k * 32 + n] : Wkv[k * 64 + (n - 32)]);
    }
  } else {
    const int ct = f - 48;
    const int n = ct * 16 + c;
    #pragma unroll
    for (int j = 0; j < 8; ++j) vv.h[j] = (__bf16)Wo[(g * 8 + j) * 256 + n];
  }
  *(bf16x8*)&wsf[item * 8] = vv.v;
}

#define FR(f) (*(const bf16x8*)&wfrag[(f)][lane][0])

__global__ __launch_bounds__(512, 2) void fused_stattn(
    const float* __restrict__ x, const __bf16* __restrict__ wsf,
    const float* __restrict__ bo, const float* __restrict__ pe,
    float* __restrict__ out) {
  __shared__ __align__(16) __bf16 wfrag[64][64][8];   // 64 KiB (all frags)
  __shared__ __align__(16) __bf16 ao_lds[8][16][40];  // per-wave bounce, 10 KiB
  __shared__ __align__(16) float bo_lds[256];
  __shared__ float pe_lds[64];

  const int tid  = threadIdx.x;
  const int lane = tid & 63;
  const int wv   = tid >> 6;
  const int g    = lane >> 4;
  const int c    = lane & 15;

  // prologue: all weight frags ws -> LDS (64 KiB = 4096 x 16B chunks)
  #pragma unroll
  for (int it = 0; it < 8; ++it) {
    const int idx = it * 512 + tid;
    *(bf16x8*)&wfrag[0][0][idx * 8] = *(const bf16x8*)&wsf[idx * 8];
  }
  if (tid < 256) bo_lds[tid] = bo[tid];
  if (tid < 64)  pe_lds[tid] = pe[tid];
  __syncthreads();

  const int slot  = blockIdx.x * 8 + wv;      // 0..4095
  const int tile0 = slot * 8;
  const f32x4* xv = (const f32x4*)x;          // row stride = 64 float4s (1 KiB)

  f32x4 xtmp[16];
  union { bf16x8 v; __bf16 h[8]; } af[8];     // A-frags: row=c, k=kt*32+g*8+j

  {  // prologue load+convert for tile0
    const int base = (tile0 * 16 + c) * 64 + g * 2;
    #pragma unroll
    for (int kt = 0; kt < 8; ++kt) {
      xtmp[2*kt]   = xv[base + kt*8];
      xtmp[2*kt+1] = xv[base + kt*8 + 1];
    }
    #pragma unroll
    for (int kt = 0; kt < 8; ++kt)
      #pragma unroll
      for (int j = 0; j < 4; ++j) {
        af[kt].h[j]   = (__bf16)xtmp[2*kt][j];
        af[kt].h[4+j] = (__bf16)xtmp[2*kt+1][j];
      }
  }

  for (int t = 0; t < 8; ++t) {
    const int tile = tile0 + t;

    // ---- GEMM1: x[16x256] @ Wqkv[256x96], B-frags from LDS ----
    f32x4 acc0 = {0,0,0,0}, acc1 = {0,0,0,0}, acc2 = {0,0,0,0};
    f32x4 acc3 = {0,0,0,0}, acc4 = {0,0,0,0}, acc5 = {0,0,0,0};
    #pragma unroll
    for (int kt = 0; kt < 8; ++kt) {
      acc0 = __builtin_amdgcn_mfma_f32_16x16x32_bf16(af[kt].v, FR(kt*6+0), acc0, 0,0,0);
      acc1 = __builtin_amdgcn_mfma_f32_16x16x32_bf16(af[kt].v, FR(kt*6+1), acc1, 0,0,0);
      acc2 = __builtin_amdgcn_mfma_f32_16x16x32_bf16(af[kt].v, FR(kt*6+2), acc2, 0,0,0);
      acc3 = __builtin_amdgcn_mfma_f32_16x16x32_bf16(af[kt].v, FR(kt*6+3), acc3, 0,0,0);
      acc4 = __builtin_amdgcn_mfma_f32_16x16x32_bf16(af[kt].v, FR(kt*6+4), acc4, 0,0,0);
      acc5 = __builtin_amdgcn_mfma_f32_16x16x32_bf16(af[kt].v, FR(kt*6+5), acc5, 0,0,0);
    }
    // C layout: lane(g,c) reg i -> row g*4+i (batch g, seq i), col c. q/k/v pairs.

    // ---- attention (in registers; 8-lane head-dim reduce via DPP) ----
    const int h0 = c >> 3;
    float ao0[4], ao1[4];
    #pragma unroll
    for (int p = 0; p < 2; ++p) {
      const f32x4 qa = p ? acc1 : acc0;
      const f32x4 ka = p ? acc3 : acc2;
      const f32x4 va = p ? acc5 : acc4;
      const int ph = 2 * p + h0;
      float sim[4][4];
      #pragma unroll
      for (int i = 0; i < 4; ++i)
        #pragma unroll
        for (int j = 0; j < 4; ++j) {
          float pr = qa[i] * ka[j];
          pr = dpp_add<0xB1>(pr);             // quad_perm xor1
          pr = dpp_add<0x4E>(pr);             // quad_perm xor2
          pr = dpp_add<0x141>(pr);            // row_half_mirror
          sim[i][j] = pr * SCALE_QK + pe_lds[ph * 16 + i * 4 + j];
        }
      #pragma unroll
      for (int i = 0; i < 4; ++i) {
        const float m = fmaxf(fmaxf(sim[i][0], sim[i][1]), fmaxf(sim[i][2], sim[i][3]));
        const float e0 = __expf(sim[i][0] - m), e1 = __expf(sim[i][1] - m);
        const float e2 = __expf(sim[i][2] - m), e3 = __expf(sim[i][3] - m);
        const float rs = 1.0f / (e0 + e1 + e2 + e3);
        const float o  = (e0*va[0] + e1*va[1] + e2*va[2] + e3*va[3]) * rs;
        if (p) ao1[i] = o; else ao0[i] = o;
      }
    }

    // ---- issue next tile's x loads NOW (in flight across GEMM2) ----
    {
      const int ntile = (tile + 1 < 32768) ? tile + 1 : tile;
      const int nbase = (ntile * 16 + c) * 64 + g * 2;
      #pragma unroll
      for (int kt = 0; kt < 8; ++kt) {
        xtmp[2*kt]   = xv[nbase + kt*8];
        xtmp[2*kt+1] = xv[nbase + kt*8 + 1];
      }
    }

    // ---- bounce C-layout -> B-frag layout for GEMM2 (per-wave private) ----
    #pragma unroll
    for (int i = 0; i < 4; ++i) {
      ao_lds[wv][g*4 + i][c]      = (__bf16)ao0[i];
      ao_lds[wv][g*4 + i][16 + c] = (__bf16)ao1[i];
    }
    const bf16x8 a2 = *(const bf16x8*)&ao_lds[wv][c][g * 8];  // col=c(=x-row), k=g*8+j

    // ---- GEMM2 (swapped): Wo^T @ ao^T, bias as C-input, float4 stores ----
    const int orow = (tile * 16 + c) * 256;
    #pragma unroll
    for (int ct = 0; ct < 16; ++ct) {
      const f32x4 bv = *(const f32x4*)&bo_lds[ct * 16 + g * 4];
      f32x4 o = __builtin_amdgcn_mfma_f32_16x16x32_bf16(FR(48 + ct), a2, bv, 0,0,0);
      *(f32x4*)&out[orow + ct * 16 + g * 4] = o;
    }

    // ---- wait + convert next tile's x to bf16 frags (fp32 temps die here) ----
    #pragma unroll
    for (int kt = 0; kt < 8; ++kt)
      #pragma unroll
      for (int j = 0; j < 4; ++j) {
        af[kt].h[j]   = (__bf16)xtmp[2*kt][j];
        af[kt].h[4+j] = (__bf16)xtmp[2*kt+1][j];
      }
  }
}

extern "C" void kernel_launch(void* const* d_in, const int* in_sizes, int n_in,
                              void* d_out, int out_size, void* d_ws, size_t ws_size,
                              hipStream_t stream) {
  const float* x   = (const float*)d_in[0];
  const float* Wq  = (const float*)d_in[1];
  const float* Wkv = (const float*)d_in[2];
  const float* Wo  = (const float*)d_in[3];
  const float* bo  = (const float*)d_in[4];
  const float* pe  = (const float*)d_in[5];
  float* out = (float*)d_out;
  __bf16* wsf = (__bf16*)d_ws;   // 64 KiB of frag-ordered bf16 weights

  hipLaunchKernelGGL(pack_weights, dim3(16), dim3(256), 0, stream, Wq, Wkv, Wo, wsf);
  hipLaunchKernelGGL(fused_stattn, dim3(512), dim3(512), 0, stream,
                     x, wsf, bo, pe, out);
}